// Round 4
// baseline (4214.507 us; speedup 1.0000x reference)
//
#include <hip/hip_runtime.h>
#include <hip/hip_bf16.h>
#include <math.h>

typedef __hip_bfloat16 bf16;

#define NT    32768   // total tokens = (b*f)*h*w = 32*1024
#define CH    320
#define NSEQ  2048    // b*d = 2*1024 temporal sequences
#define FRAMES 16
#define HEADS 8
#define DHEAD 40
#define INNER 1280
#define HW    1024
#define NIMG  32      // b*f images

__device__ __forceinline__ float b2f(bf16 v) { return __bfloat162float(v); }
__device__ __forceinline__ bf16  f2b(float v) { return __float2bfloat16(v); }

// Dtype-agnostic input load (inputs proven fp32 on this harness; probe kept as
// a zero-cost guard). probe = gn_w (exactly 1.0): first u16 is 0x3F80 iff bf16.
__device__ __forceinline__ bool probe_is_bf16(const void* probe) {
  return *(const unsigned short*)probe == 0x3F80u;
}
__device__ __forceinline__ float ldin(const void* p, size_t i, bool isbf) {
  return isbf ? b2f(((const bf16*)p)[i]) : ((const float*)p)[i];
}

// ---- block-wide sum reduction (any blockDim multiple of 64, <=512) ----
__device__ __forceinline__ float block_reduce_sum(float v, float* sbuf) {
  int lane = threadIdx.x & 63;
  int wv   = threadIdx.x >> 6;
#pragma unroll
  for (int off = 32; off; off >>= 1) v += __shfl_down(v, off);
  __syncthreads();                    // protect sbuf from prior use
  if (lane == 0) sbuf[wv] = v;
  __syncthreads();
  int nw = ((int)blockDim.x + 63) >> 6;
  float r = 0.f;
  for (int i = 0; i < nw; ++i) r += sbuf[i];
  return r;
}

// ---- GroupNorm stats: one block per (image, group); group = 10 ch x 1024 ----
__global__ __launch_bounds__(256) void gn_stats_kernel(const void* __restrict__ x,
                                                       float* __restrict__ stat,
                                                       const void* __restrict__ probe) {
  __shared__ float sbuf[8];
  bool isbf = probe_is_bf16(probe);
  int g  = blockIdx.x;   // 0..31
  int im = blockIdx.y;   // 0..31
  size_t base = ((size_t)im * CH + (size_t)g * 10) * HW;
  float s = 0.f, s2 = 0.f;
  for (int i = threadIdx.x; i < 10 * HW; i += 256) {
    float v = ldin(x, base + i, isbf);
    s += v; s2 += v * v;
  }
  s  = block_reduce_sum(s, sbuf);
  s2 = block_reduce_sum(s2, sbuf);
  if (threadIdx.x == 0) {
    float mean = s * (1.f / 10240.f);
    float var  = s2 * (1.f / 10240.f) - mean * mean;
    stat[(im * 32 + g) * 2 + 0] = mean;
    stat[(im * 32 + g) * 2 + 1] = rsqrtf(var + 1e-6f);
  }
}

// ---- GN apply + transpose [img][c][s] -> tokens [(img*1024+s)][c] ----
__global__ __launch_bounds__(256) void gn_apply_kernel(const void* __restrict__ x,
                                                       const void* __restrict__ gw,
                                                       const void* __restrict__ gb,
                                                       const float* __restrict__ stat,
                                                       bf16* __restrict__ xn) {
  __shared__ float tile[32][33];
  bool isbf = probe_is_bf16(gw);
  int st = blockIdx.x, ct = blockIdx.y, im = blockIdx.z;
  int c0 = ct * 32, s0 = st * 32;
  for (int t = threadIdx.x; t < 1024; t += 256) {
    int i = t >> 5, j = t & 31;     // i: channel in tile, j: spatial in tile
    int c = c0 + i;
    int g = c / 10;
    float mean = stat[(im * 32 + g) * 2 + 0];
    float rstd = stat[(im * 32 + g) * 2 + 1];
    float v = (ldin(x, ((size_t)(im * CH + c) << 10) + s0 + j, isbf) - mean) * rstd
              * ldin(gw, c, isbf) + ldin(gb, c, isbf);
    tile[i][j] = v;
  }
  __syncthreads();
  for (int t = threadIdx.x; t < 1024; t += 256) {
    int i = t >> 5, j = t & 31;     // i: spatial, j: channel
    xn[((size_t)(im * HW + s0 + i)) * CH + c0 + j] = f2b(tile[j][i]);
  }
}

// ---- generic tiled GEMM: C[M,N] = A[M,K] @ B[K,N] (+bias) (+res) ----
// A,res,C are bf16 ws buffers; B,bias come from d_in (dtype-probed).
__global__ __launch_bounds__(256) void gemm_bias_kernel(const bf16* __restrict__ A,
                                                        const void* __restrict__ B,
                                                        const void* __restrict__ bias,
                                                        const bf16* __restrict__ res,
                                                        bf16* __restrict__ C,
                                                        const void* __restrict__ probe,
                                                        int M, int N, int K) {
  __shared__ float As[64][17];
  __shared__ float Bs[16][65];
  bool isbf = probe_is_bf16(probe);
  int tid = threadIdx.x;
  int m0 = blockIdx.x * 64;
  int n0 = blockIdx.y * 64;
  int tr = tid >> 4, tc = tid & 15;
  int tr4 = tr * 4, tc4 = tc * 4;
  float acc[4][4] = {};
  for (int k0 = 0; k0 < K; k0 += 16) {
    for (int t = tid; t < 64 * 16; t += 256) {
      int r = t >> 4, c = t & 15;
      As[r][c] = b2f(A[(size_t)(m0 + r) * K + k0 + c]);
    }
    for (int t = tid; t < 16 * 64; t += 256) {
      int r = t >> 6, c = t & 63;
      Bs[r][c] = ldin(B, (size_t)(k0 + r) * N + n0 + c, isbf);
    }
    __syncthreads();
#pragma unroll
    for (int kk = 0; kk < 16; ++kk) {
      float a[4], b[4];
#pragma unroll
      for (int i = 0; i < 4; ++i) a[i] = As[tr4 + i][kk];
#pragma unroll
      for (int j = 0; j < 4; ++j) b[j] = Bs[kk][tc4 + j];
#pragma unroll
      for (int i = 0; i < 4; ++i)
#pragma unroll
        for (int j = 0; j < 4; ++j)
          acc[i][j] = fmaf(a[i], b[j], acc[i][j]);
    }
    __syncthreads();
  }
#pragma unroll
  for (int i = 0; i < 4; ++i) {
    size_t rowoff = (size_t)(m0 + tr4 + i) * N + n0;
#pragma unroll
    for (int j = 0; j < 4; ++j) {
      float v = acc[i][j];
      if (bias) v += ldin(bias, n0 + tc4 + j, isbf);
      if (res)  v += b2f(res[rowoff + tc4 + j]);
      C[rowoff + tc4 + j] = f2b(v);
    }
  }
}

// ---- GEGLU FF1: act = (A@W1a+b1a) * gelu(A@W1g+b1g) ----
__global__ __launch_bounds__(256) void gemm_geglu_kernel(const bf16* __restrict__ A,
                                                         const void* __restrict__ W1,
                                                         const void* __restrict__ b1,
                                                         bf16* __restrict__ actout,
                                                         const void* __restrict__ probe,
                                                         int M, int K) {
  __shared__ float As[64][17];
  __shared__ float Ba[16][65];
  __shared__ float Bg[16][65];
  bool isbf = probe_is_bf16(probe);
  int tid = threadIdx.x;
  int m0 = blockIdx.x * 64;
  int n0 = blockIdx.y * 64;
  int tr = tid >> 4, tc = tid & 15;
  int tr4 = tr * 4, tc4 = tc * 4;
  float acc_a[4][4] = {};
  float acc_g[4][4] = {};
  const int NW = 2 * INNER;  // 2560
  for (int k0 = 0; k0 < K; k0 += 16) {
    for (int t = tid; t < 64 * 16; t += 256) {
      int r = t >> 4, c = t & 15;
      As[r][c] = b2f(A[(size_t)(m0 + r) * K + k0 + c]);
    }
    for (int t = tid; t < 16 * 64; t += 256) {
      int r = t >> 6, c = t & 63;
      Ba[r][c] = ldin(W1, (size_t)(k0 + r) * NW + n0 + c, isbf);
      Bg[r][c] = ldin(W1, (size_t)(k0 + r) * NW + INNER + n0 + c, isbf);
    }
    __syncthreads();
#pragma unroll
    for (int kk = 0; kk < 16; ++kk) {
      float a[4], ba[4], bg[4];
#pragma unroll
      for (int i = 0; i < 4; ++i) a[i] = As[tr4 + i][kk];
#pragma unroll
      for (int j = 0; j < 4; ++j) { ba[j] = Ba[kk][tc4 + j]; bg[j] = Bg[kk][tc4 + j]; }
#pragma unroll
      for (int i = 0; i < 4; ++i)
#pragma unroll
        for (int j = 0; j < 4; ++j) {
          acc_a[i][j] = fmaf(a[i], ba[j], acc_a[i][j]);
          acc_g[i][j] = fmaf(a[i], bg[j], acc_g[i][j]);
        }
    }
    __syncthreads();
  }
#pragma unroll
  for (int i = 0; i < 4; ++i) {
    size_t rowoff = (size_t)(m0 + tr4 + i) * INNER + n0;
#pragma unroll
    for (int j = 0; j < 4; ++j) {
      float av = acc_a[i][j] + ldin(b1, n0 + tc4 + j, isbf);
      float gv = acc_g[i][j] + ldin(b1, INNER + n0 + tc4 + j, isbf);
      float gelu = 0.5f * gv * (1.0f + erff(gv * 0.70710678118654752f));
      actout[rowoff + tc4 + j] = f2b(av * gelu);
    }
  }
}

// ---- LayerNorm over C=320, one block per token row ----
__global__ __launch_bounds__(320) void layernorm_kernel(const bf16* __restrict__ in,
                                                        const void* __restrict__ w,
                                                        const void* __restrict__ b,
                                                        bf16* __restrict__ out) {
  __shared__ float sbuf[8];
  bool isbf = probe_is_bf16(w);  // LN weight is exactly 1.0 too
  int row = blockIdx.x;
  int c = threadIdx.x;
  size_t idx = (size_t)row * CH + c;
  float x = b2f(in[idx]);
  float mean = block_reduce_sum(x, sbuf) * (1.f / 320.f);
  float d = x - mean;
  float var = block_reduce_sum(d * d, sbuf) * (1.f / 320.f);
  float rstd = rsqrtf(var + 1e-5f);
  out[idx] = f2b(d * rstd * ldin(w, c, isbf) + ldin(b, c, isbf));
}

// ---- rearrange (b f) d c -> (b d) f c, plus temporal PE add ----
__global__ __launch_bounds__(320) void to_temporal_kernel(const bf16* __restrict__ in,
                                                          bf16* __restrict__ tout) {
  int row = blockIdx.x;            // t-order row = n*16 + fi
  int c = threadIdx.x;
  int n = row >> 4, fi = row & 15;
  int b = n >> 10, d = n & 1023;
  int src = ((b << 4) + fi) * HW + d;
  float div = expf(-(float)(c & ~1) * (9.210340371976184f / 320.0f));
  float arg = (float)fi * div;
  float pe = (c & 1) ? cosf(arg) : sinf(arg);
  tout[(size_t)row * CH + c] = f2b(b2f(in[(size_t)src * CH + c]) + pe);
}

// ---- rearrange back (b d) f c -> (b f) d c with residual add into hs ----
__global__ __launch_bounds__(320) void from_temporal_res_kernel(const bf16* __restrict__ proj,
                                                                bf16* __restrict__ hs) {
  int row = blockIdx.x;            // t-order row
  int c = threadIdx.x;
  int n = row >> 4, fi = row & 15;
  int b = n >> 10, d = n & 1023;
  int dst = ((b << 4) + fi) * HW + d;
  size_t di = (size_t)dst * CH + c;
  hs[di] = f2b(b2f(hs[di]) + b2f(proj[(size_t)row * CH + c]));
}

// ---- temporal attention core: one block per sequence n (2048 seqs, f=16) ----
__global__ __launch_bounds__(256) void attention_kernel(const bf16* __restrict__ Q,
                                                        const bf16* __restrict__ K,
                                                        const bf16* __restrict__ V,
                                                        bf16* __restrict__ O) {
  __shared__ float qs[FRAMES * CH];   // 20 KB; reused for V after scores
  __shared__ float ks[FRAMES * CH];   // 20 KB
  __shared__ float sc[HEADS * FRAMES * FRAMES];  // 8 KB
  const float SCALE = 0.15811388300841897f;      // 40^-0.5
  int n = blockIdx.x;
  size_t base = (size_t)n * FRAMES * CH;
  for (int t = threadIdx.x; t < FRAMES * CH; t += 256) {
    qs[t] = b2f(Q[base + t]) * SCALE;
    ks[t] = b2f(K[base + t]);
  }
  __syncthreads();
  for (int e = threadIdx.x; e < HEADS * FRAMES * FRAMES; e += 256) {
    int h = e >> 8, qf = (e >> 4) & 15, kf = e & 15;
    const float* qp = &qs[qf * CH + h * DHEAD];
    const float* kp = &ks[kf * CH + h * DHEAD];
    float s = 0.f;
#pragma unroll
    for (int d = 0; d < DHEAD; ++d) s = fmaf(qp[d], kp[d], s);
    sc[e] = s;
  }
  __syncthreads();
  // V load into qs (Q no longer needed) overlaps softmax on sc
  for (int t = threadIdx.x; t < FRAMES * CH; t += 256) qs[t] = b2f(V[base + t]);
  if (threadIdx.x < HEADS * FRAMES) {
    float* r = &sc[threadIdx.x * FRAMES];
    float mx = r[0];
#pragma unroll
    for (int i = 1; i < FRAMES; ++i) mx = fmaxf(mx, r[i]);
    float sum = 0.f;
#pragma unroll
    for (int i = 0; i < FRAMES; ++i) { float e2 = expf(r[i] - mx); r[i] = e2; sum += e2; }
    float inv = 1.0f / sum;
#pragma unroll
    for (int i = 0; i < FRAMES; ++i) r[i] *= inv;
  }
  __syncthreads();
  for (int t = threadIdx.x; t < FRAMES * CH; t += 256) {
    int qf = t / CH, c = t % CH, h = c / DHEAD;
    const float* p = &sc[(h * FRAMES + qf) * FRAMES];
    float s = 0.f;
#pragma unroll
    for (int kf = 0; kf < FRAMES; ++kf) s = fmaf(p[kf], qs[kf * CH + c], s);
    O[base + t] = f2b(s);
  }
}

// ---- final: tokens -> [img][c][s] + spatial residual x; OUTPUT IS FP32 ----
__global__ __launch_bounds__(256) void final_kernel(const bf16* __restrict__ proj,
                                                    const void* __restrict__ x,
                                                    float* __restrict__ out,
                                                    const void* __restrict__ probe) {
  __shared__ float tile[32][33];
  bool isbf = probe_is_bf16(probe);
  int st = blockIdx.x, ct = blockIdx.y, im = blockIdx.z;
  int c0 = ct * 32, s0 = st * 32;
  for (int t = threadIdx.x; t < 1024; t += 256) {
    int i = t >> 5, j = t & 31;   // i: spatial, j: channel
    tile[i][j] = b2f(proj[((size_t)(im * HW + s0 + i)) * CH + c0 + j]);
  }
  __syncthreads();
  for (int t = threadIdx.x; t < 1024; t += 256) {
    int i = t >> 5, j = t & 31;   // i: channel, j: spatial
    size_t idx = ((size_t)(im * CH + c0 + i) << 10) + s0 + j;
    out[idx] = tile[j][i] + ldin(x, idx, isbf);
  }
}

extern "C" void kernel_launch(void* const* d_in, const int* in_sizes, int n_in,
                              void* d_out, int out_size, void* d_ws, size_t ws_size,
                              hipStream_t stream) {
  const void* x      = d_in[0];
  const void* gn_w   = d_in[1];   // == 1.0 everywhere: also the dtype probe
  const void* gn_b   = d_in[2];
  const void* pin_w  = d_in[3];
  const void* pin_b  = d_in[4];
  const void* ffln_w = d_in[19];
  const void* ffln_b = d_in[20];
  const void* ff_w1  = d_in[21];
  const void* ff_b1  = d_in[22];
  const void* ff_w2  = d_in[23];
  const void* ff_b2  = d_in[24];
  const void* pout_w = d_in[25];
  const void* pout_b = d_in[26];
  const void* probe  = gn_w;

  const size_t NTC = (size_t)NT * CH;            // 10,485,760 elements
  bf16* W0 = (bf16*)d_ws;        // hs (persistent residual stream)
  bf16* W1 = W0 + NTC;
  bf16* W2 = W1 + NTC;
  bf16* W3 = W2 + NTC;
  // d_out is FP32 (out_size fp32 elements = 41.9 MB); use it as bf16 scratch
  // (21 MB) + gnstat (8 KB) until final_kernel overwrites it entirely.
  bf16* OB = (bf16*)d_out;
  float* gnstat = (float*)d_out;

  dim3 g_trans(32, 10, NIMG);                     // spatial x channel x images
  dim3 g_gemm(NT / 64, CH / 64);                  // 512 x 5

  // GroupNorm -> tokens
  gn_stats_kernel<<<dim3(32, NIMG), 256, 0, stream>>>(x, gnstat, probe);
  gn_apply_kernel<<<g_trans, 256, 0, stream>>>(x, gn_w, gn_b, gnstat, W1);
  // proj_in
  gemm_bias_kernel<<<g_gemm, 256, 0, stream>>>(W1, pin_w, pin_b, nullptr, W0, probe, NT, CH, CH);

  for (int blk = 0; blk < 2; ++blk) {
    const void* lnw = d_in[5 + 7 * blk];
    const void* lnb = d_in[6 + 7 * blk];
    const void* wq  = d_in[7 + 7 * blk];
    const void* wk  = d_in[8 + 7 * blk];
    const void* wv  = d_in[9 + 7 * blk];
    const void* wo  = d_in[10 + 7 * blk];
    const void* bo  = d_in[11 + 7 * blk];

    layernorm_kernel<<<NT, 320, 0, stream>>>(W0, lnw, lnb, W1);
    to_temporal_kernel<<<NT, 320, 0, stream>>>(W1, W2);          // W2 = t (+PE)
    gemm_bias_kernel<<<g_gemm, 256, 0, stream>>>(W2, wq, nullptr, nullptr, W3, probe, NT, CH, CH); // Q
    gemm_bias_kernel<<<g_gemm, 256, 0, stream>>>(W2, wk, nullptr, nullptr, OB, probe, NT, CH, CH); // K
    gemm_bias_kernel<<<g_gemm, 256, 0, stream>>>(W2, wv, nullptr, nullptr, W1, probe, NT, CH, CH); // V
    attention_kernel<<<NSEQ, 256, 0, stream>>>(W3, OB, W1, W2);  // W2 = attn out (t-order)
    gemm_bias_kernel<<<g_gemm, 256, 0, stream>>>(W2, wo, bo, nullptr, W3, probe, NT, CH, CH);      // o proj
    from_temporal_res_kernel<<<NT, 320, 0, stream>>>(W3, W0);    // hs += rearranged
  }

  // FF (GEGLU), chunked over M halves so act (Mh x 1280) fits in W2+W3
  layernorm_kernel<<<NT, 320, 0, stream>>>(W0, ffln_w, ffln_b, W1);
  const int MH = NT / 2;  // 16384 rows per chunk
  for (int h = 0; h < 2; ++h) {
    const bf16* Ah = W1 + (size_t)h * MH * CH;
    bf16* act = W2;                       // spans W2..W3 = MH*1280 elements
    gemm_geglu_kernel<<<dim3(MH / 64, INNER / 64), 256, 0, stream>>>(Ah, ff_w1, ff_b1, act, probe, MH, CH);
    bf16* hsh = W0 + (size_t)h * MH * CH;
    gemm_bias_kernel<<<dim3(MH / 64, CH / 64), 256, 0, stream>>>(act, ff_w2, ff_b2, hsh, hsh, probe, MH, CH, INNER);
  }

  // proj_out + spatial residual (fp32 output)
  gemm_bias_kernel<<<g_gemm, 256, 0, stream>>>(W0, pout_w, pout_b, nullptr, W1, probe, NT, CH, CH);
  final_kernel<<<g_trans, 256, 0, stream>>>(W1, x, (float*)d_out, probe);
}

// Round 5
// 878.029 us; speedup vs baseline: 4.8000x; 4.8000x over previous
//
#include <hip/hip_runtime.h>
#include <hip/hip_bf16.h>
#include <math.h>

typedef __hip_bfloat16 bf16;
typedef __attribute__((ext_vector_type(8))) short bf16x8;   // 8 bf16 = 4 VGPRs
typedef __attribute__((ext_vector_type(4))) float f32x4;

#define NT    32768   // total tokens = (b*f)*h*w = 32*1024
#define CH    320
#define NSEQ  2048    // b*d temporal sequences
#define FRAMES 16
#define HEADS 8
#define DHEAD 40
#define INNER 1280
#define HW    1024
#define NIMG  32      // b*f images

__device__ __forceinline__ float b2f(bf16 v) { return __bfloat162float(v); }
__device__ __forceinline__ bf16  f2b(float v) { return __float2bfloat16(v); }

// async global->LDS 16B: LDS dst = wave-uniform base + lane*16 (HW-scattered)
__device__ __forceinline__ void stage16(const bf16* g, bf16* l) {
  __builtin_amdgcn_global_load_lds(
      (const __attribute__((address_space(1))) void*)g,
      (__attribute__((address_space(3))) void*)l, 16, 0, 0);
}

// ---- block-wide sum reduction ----
__device__ __forceinline__ float block_reduce_sum(float v, float* sbuf) {
  int lane = threadIdx.x & 63;
  int wv   = threadIdx.x >> 6;
#pragma unroll
  for (int off = 32; off; off >>= 1) v += __shfl_down(v, off);
  __syncthreads();
  if (lane == 0) sbuf[wv] = v;
  __syncthreads();
  int nw = ((int)blockDim.x + 63) >> 6;
  float r = 0.f;
  for (int i = 0; i < nw; ++i) r += sbuf[i];
  return r;
}

// ---- weight transpose+cast: [K][N] fp32 -> [N][K] bf16, batched ----
struct TD { const float* src; bf16* dst; int K, N, t0; };
struct TDs { TD d[12]; };
__global__ __launch_bounds__(256) void transpose_w_kernel(TDs td, int ndesc) {
  __shared__ float tile[32][33];
  int bt = blockIdx.x;
  int mi = 0;
  for (int i = 1; i < 12; ++i) if (i < ndesc && bt >= td.d[i].t0) mi = i;
  TD e = td.d[mi];
  int lt = bt - e.t0;
  int ntx = e.N >> 5;
  int kt = lt / ntx, nt = lt - kt * ntx;
#pragma unroll
  for (int q = 0; q < 4; ++q) {
    int idx = threadIdx.x + q * 256; int r = idx >> 5, c = idx & 31;
    tile[r][c] = e.src[(size_t)(kt * 32 + r) * e.N + nt * 32 + c];
  }
  __syncthreads();
#pragma unroll
  for (int q = 0; q < 4; ++q) {
    int idx = threadIdx.x + q * 256; int r = idx >> 5, c = idx & 31;
    e.dst[(size_t)(nt * 32 + r) * e.K + kt * 32 + c] = f2b(tile[c][r]);
  }
}

// ---- MFMA GEMM: C = A[M,K] @ BT[N,K]^T (+bias fp32) (+res bf16) ----
// BM=128, BN=64, BK=64; 256 thr = 4 waves (2x2), wave tile 64x32.
// Output width is always 320; for QKV (NTOT=960) dst splits by n0/320.
__global__ __launch_bounds__(256) void gemm_mfma_kernel(
    const bf16* __restrict__ A, const bf16* __restrict__ BT,
    const float* __restrict__ bias, const bf16* __restrict__ res,
    bf16* __restrict__ C0, bf16* __restrict__ C1, bf16* __restrict__ C2,
    int M, int K) {
  __shared__ __align__(16) bf16 sA[128 * 64];
  __shared__ __align__(16) bf16 sB[64 * 64];
  int tid = threadIdx.x, lane = tid & 63, w = tid >> 6;
  int wm = w >> 1, wn = w & 1;
  int m0 = blockIdx.x * 128, n0 = blockIdx.y * 64;
  int which = n0 / 320;
  int ncol0 = n0 - which * 320;
  bf16* C = which == 0 ? C0 : (which == 1 ? C1 : C2);
  f32x4 acc[4][2];
#pragma unroll
  for (int i = 0; i < 4; ++i)
#pragma unroll
    for (int j = 0; j < 2; ++j) acc[i][j] = (f32x4){0.f, 0.f, 0.f, 0.f};

  int lr = lane >> 3;            // row-in-8 for staging
  int cg = (lane & 7) ^ lr;      // swizzled global chunk
  for (int k0 = 0; k0 < K; k0 += 64) {
#pragma unroll
    for (int s = 0; s < 4; ++s) {        // A: 16 KB = 16 instrs, 4/wave
      int tA = w * 4 + s;
      int row = tA * 8 + lr;
      stage16(A + (size_t)(m0 + row) * K + k0 + cg * 8, sA + tA * 512);
    }
#pragma unroll
    for (int s = 0; s < 2; ++s) {        // B: 8 KB = 8 instrs, 2/wave
      int tB = w * 2 + s;
      int row = tB * 8 + lr;
      stage16(BT + (size_t)(n0 + row) * K + k0 + cg * 8, sB + tB * 512);
    }
    __syncthreads();
#pragma unroll
    for (int kk = 0; kk < 2; ++kk) {
      bf16x8 a[4], b[2];
      int cc = kk * 4 + (lane >> 4);
#pragma unroll
      for (int i = 0; i < 4; ++i) {
        int r = wm * 64 + i * 16 + (lane & 15);
        a[i] = *(const bf16x8*)(sA + r * 64 + ((cc ^ (r & 7)) * 8));
      }
#pragma unroll
      for (int j = 0; j < 2; ++j) {
        int n = wn * 32 + j * 16 + (lane & 15);
        b[j] = *(const bf16x8*)(sB + n * 64 + ((cc ^ (n & 7)) * 8));
      }
#pragma unroll
      for (int i = 0; i < 4; ++i)
#pragma unroll
        for (int j = 0; j < 2; ++j)
          acc[i][j] = __builtin_amdgcn_mfma_f32_16x16x32_bf16(a[i], b[j], acc[i][j], 0, 0, 0);
    }
    __syncthreads();
  }
  // epilogue: C/D layout col=lane&15, row=(lane>>4)*4+reg
#pragma unroll
  for (int i = 0; i < 4; ++i)
#pragma unroll
    for (int j = 0; j < 2; ++j) {
      int row0 = m0 + wm * 64 + i * 16 + (lane >> 4) * 4;
      int col  = ncol0 + wn * 32 + j * 16 + (lane & 15);
      float bv = bias ? bias[col] : 0.f;
#pragma unroll
      for (int rg = 0; rg < 4; ++rg) {
        size_t idx = (size_t)(row0 + rg) * 320 + col;
        float v = acc[i][j][rg] + bv;
        if (res) v += b2f(res[idx]);
        C[idx] = f2b(v);
      }
    }
}

// ---- MFMA GEGLU GEMM: act = (A@W1a+b1a) * gelu(A@W1g+b1g) ----
// BT = ff_w1^T [2560][320]; a-rows n, gate-rows 1280+n. Output [M][1280].
__global__ __launch_bounds__(256) void gemm_mfma_geglu_kernel(
    const bf16* __restrict__ A, const bf16* __restrict__ BT,
    const float* __restrict__ b1, bf16* __restrict__ act, int M, int K) {
  __shared__ __align__(16) bf16 sA[128 * 64];
  __shared__ __align__(16) bf16 sBa[64 * 64];
  __shared__ __align__(16) bf16 sBg[64 * 64];
  int tid = threadIdx.x, lane = tid & 63, w = tid >> 6;
  int wm = w >> 1, wn = w & 1;
  int m0 = blockIdx.x * 128, n0 = blockIdx.y * 64;
  f32x4 aa[4][2], ag[4][2];
#pragma unroll
  for (int i = 0; i < 4; ++i)
#pragma unroll
    for (int j = 0; j < 2; ++j) {
      aa[i][j] = (f32x4){0.f, 0.f, 0.f, 0.f};
      ag[i][j] = (f32x4){0.f, 0.f, 0.f, 0.f};
    }
  int lr = lane >> 3;
  int cg = (lane & 7) ^ lr;
  for (int k0 = 0; k0 < K; k0 += 64) {
#pragma unroll
    for (int s = 0; s < 4; ++s) {
      int tA = w * 4 + s;
      int row = tA * 8 + lr;
      stage16(A + (size_t)(m0 + row) * K + k0 + cg * 8, sA + tA * 512);
    }
#pragma unroll
    for (int s = 0; s < 2; ++s) {
      int tB = w * 2 + s;
      int row = tB * 8 + lr;
      stage16(BT + (size_t)(n0 + row) * K + k0 + cg * 8, sBa + tB * 512);
      stage16(BT + (size_t)(1280 + n0 + row) * K + k0 + cg * 8, sBg + tB * 512);
    }
    __syncthreads();
#pragma unroll
    for (int kk = 0; kk < 2; ++kk) {
      bf16x8 a[4], ba[2], bg[2];
      int cc = kk * 4 + (lane >> 4);
#pragma unroll
      for (int i = 0; i < 4; ++i) {
        int r = wm * 64 + i * 16 + (lane & 15);
        a[i] = *(const bf16x8*)(sA + r * 64 + ((cc ^ (r & 7)) * 8));
      }
#pragma unroll
      for (int j = 0; j < 2; ++j) {
        int n = wn * 32 + j * 16 + (lane & 15);
        ba[j] = *(const bf16x8*)(sBa + n * 64 + ((cc ^ (n & 7)) * 8));
        bg[j] = *(const bf16x8*)(sBg + n * 64 + ((cc ^ (n & 7)) * 8));
      }
#pragma unroll
      for (int i = 0; i < 4; ++i)
#pragma unroll
        for (int j = 0; j < 2; ++j) {
          aa[i][j] = __builtin_amdgcn_mfma_f32_16x16x32_bf16(a[i], ba[j], aa[i][j], 0, 0, 0);
          ag[i][j] = __builtin_amdgcn_mfma_f32_16x16x32_bf16(a[i], bg[j], ag[i][j], 0, 0, 0);
        }
    }
    __syncthreads();
  }
#pragma unroll
  for (int i = 0; i < 4; ++i)
#pragma unroll
    for (int j = 0; j < 2; ++j) {
      int row0 = m0 + wm * 64 + i * 16 + (lane >> 4) * 4;
      int col  = n0 + wn * 32 + j * 16 + (lane & 15);
      float bva = b1[col], bvg = b1[1280 + col];
#pragma unroll
      for (int rg = 0; rg < 4; ++rg) {
        float av = aa[i][j][rg] + bva;
        float gv = ag[i][j][rg] + bvg;
        float gelu = 0.5f * gv * (1.0f + erff(gv * 0.70710678118654752f));
        act[(size_t)(row0 + rg) * 1280 + col] = f2b(av * gelu);
      }
    }
}

// ---- GroupNorm stats ----
__global__ __launch_bounds__(256) void gn_stats_kernel(const float* __restrict__ x,
                                                       float* __restrict__ stat) {
  __shared__ float sbuf[8];
  int g  = blockIdx.x;   // 0..31
  int im = blockIdx.y;   // 0..31
  const float* base = x + ((size_t)im * CH + (size_t)g * 10) * HW;
  float s = 0.f, s2 = 0.f;
  for (int i = threadIdx.x; i < 10 * HW; i += 256) {
    float v = base[i];
    s += v; s2 += v * v;
  }
  s  = block_reduce_sum(s, sbuf);
  s2 = block_reduce_sum(s2, sbuf);
  if (threadIdx.x == 0) {
    float mean = s * (1.f / 10240.f);
    float var  = s2 * (1.f / 10240.f) - mean * mean;
    stat[(im * 32 + g) * 2 + 0] = mean;
    stat[(im * 32 + g) * 2 + 1] = rsqrtf(var + 1e-6f);
  }
}

// ---- GN apply + transpose [img][c][s] -> tokens ----
__global__ __launch_bounds__(256) void gn_apply_kernel(const float* __restrict__ x,
                                                       const float* __restrict__ gw,
                                                       const float* __restrict__ gb,
                                                       const float* __restrict__ stat,
                                                       bf16* __restrict__ xn) {
  __shared__ float tile[32][33];
  int st = blockIdx.x, ct = blockIdx.y, im = blockIdx.z;
  int c0 = ct * 32, s0 = st * 32;
  for (int t = threadIdx.x; t < 1024; t += 256) {
    int i = t >> 5, j = t & 31;
    int c = c0 + i;
    int g = c / 10;
    float mean = stat[(im * 32 + g) * 2 + 0];
    float rstd = stat[(im * 32 + g) * 2 + 1];
    tile[i][j] = (x[((size_t)(im * CH + c) << 10) + s0 + j] - mean) * rstd * gw[c] + gb[c];
  }
  __syncthreads();
  for (int t = threadIdx.x; t < 1024; t += 256) {
    int i = t >> 5, j = t & 31;
    xn[((size_t)(im * HW + s0 + i)) * CH + c0 + j] = f2b(tile[j][i]);
  }
}

// ---- LayerNorm over C=320 ----
__global__ __launch_bounds__(320) void layernorm_kernel(const bf16* __restrict__ in,
                                                        const float* __restrict__ w,
                                                        const float* __restrict__ b,
                                                        bf16* __restrict__ out) {
  __shared__ float sbuf[8];
  int row = blockIdx.x;
  int c = threadIdx.x;
  size_t idx = (size_t)row * CH + c;
  float x = b2f(in[idx]);
  float mean = block_reduce_sum(x, sbuf) * (1.f / 320.f);
  float d = x - mean;
  float var = block_reduce_sum(d * d, sbuf) * (1.f / 320.f);
  float rstd = rsqrtf(var + 1e-5f);
  out[idx] = f2b(d * rstd * w[c] + b[c]);
}

// ---- rearrange (b f) d c -> (b d) f c, + temporal PE ----
__global__ __launch_bounds__(320) void to_temporal_kernel(const bf16* __restrict__ in,
                                                          bf16* __restrict__ tout) {
  int row = blockIdx.x;
  int c = threadIdx.x;
  int n = row >> 4, fi = row & 15;
  int b = n >> 10, d = n & 1023;
  int src = ((b << 4) + fi) * HW + d;
  float div = expf(-(float)(c & ~1) * (9.210340371976184f / 320.0f));
  float arg = (float)fi * div;
  float pe = (c & 1) ? cosf(arg) : sinf(arg);
  tout[(size_t)row * CH + c] = f2b(b2f(in[(size_t)src * CH + c]) + pe);
}

// ---- rearrange back with residual add into hs ----
__global__ __launch_bounds__(320) void from_temporal_res_kernel(const bf16* __restrict__ proj,
                                                                bf16* __restrict__ hs) {
  int row = blockIdx.x;
  int c = threadIdx.x;
  int n = row >> 4, fi = row & 15;
  int b = n >> 10, d = n & 1023;
  int dst = ((b << 4) + fi) * HW + d;
  size_t di = (size_t)dst * CH + c;
  hs[di] = f2b(b2f(hs[di]) + b2f(proj[(size_t)row * CH + c]));
}

// ---- temporal attention: one block per sequence ----
__global__ __launch_bounds__(256) void attention_kernel(const bf16* __restrict__ Q,
                                                        const bf16* __restrict__ K,
                                                        const bf16* __restrict__ V,
                                                        bf16* __restrict__ O) {
  __shared__ float qs[FRAMES * CH];
  __shared__ float ks[FRAMES * CH];
  __shared__ float sc[HEADS * FRAMES * FRAMES];
  const float SCALE = 0.15811388300841897f;
  int n = blockIdx.x;
  size_t base = (size_t)n * FRAMES * CH;
  for (int t = threadIdx.x; t < FRAMES * CH; t += 256) {
    qs[t] = b2f(Q[base + t]) * SCALE;
    ks[t] = b2f(K[base + t]);
  }
  __syncthreads();
  for (int e = threadIdx.x; e < HEADS * FRAMES * FRAMES; e += 256) {
    int h = e >> 8, qf = (e >> 4) & 15, kf = e & 15;
    const float* qp = &qs[qf * CH + h * DHEAD];
    const float* kp = &ks[kf * CH + h * DHEAD];
    float s = 0.f;
#pragma unroll
    for (int d = 0; d < DHEAD; ++d) s = fmaf(qp[d], kp[d], s);
    sc[e] = s;
  }
  __syncthreads();
  for (int t = threadIdx.x; t < FRAMES * CH; t += 256) qs[t] = b2f(V[base + t]);
  if (threadIdx.x < HEADS * FRAMES) {
    float* r = &sc[threadIdx.x * FRAMES];
    float mx = r[0];
#pragma unroll
    for (int i = 1; i < FRAMES; ++i) mx = fmaxf(mx, r[i]);
    float sum = 0.f;
#pragma unroll
    for (int i = 0; i < FRAMES; ++i) { float e2 = expf(r[i] - mx); r[i] = e2; sum += e2; }
    float inv = 1.0f / sum;
#pragma unroll
    for (int i = 0; i < FRAMES; ++i) r[i] *= inv;
  }
  __syncthreads();
  for (int t = threadIdx.x; t < FRAMES * CH; t += 256) {
    int qf = t / CH, c = t % CH, h = c / DHEAD;
    const float* p = &sc[(h * FRAMES + qf) * FRAMES];
    float s = 0.f;
#pragma unroll
    for (int kf = 0; kf < FRAMES; ++kf) s = fmaf(p[kf], qs[kf * CH + c], s);
    O[base + t] = f2b(s);
  }
}

// ---- final: tokens -> [img][c][s] + fp32 spatial residual; fp32 out ----
__global__ __launch_bounds__(256) void final_kernel(const bf16* __restrict__ proj,
                                                    const float* __restrict__ x,
                                                    float* __restrict__ out) {
  __shared__ float tile[32][33];
  int st = blockIdx.x, ct = blockIdx.y, im = blockIdx.z;
  int c0 = ct * 32, s0 = st * 32;
  for (int t = threadIdx.x; t < 1024; t += 256) {
    int i = t >> 5, j = t & 31;
    tile[i][j] = b2f(proj[((size_t)(im * HW + s0 + i)) * CH + c0 + j]);
  }
  __syncthreads();
  for (int t = threadIdx.x; t < 1024; t += 256) {
    int i = t >> 5, j = t & 31;
    size_t idx = ((size_t)(im * CH + c0 + i) << 10) + s0 + j;
    out[idx] = tile[j][i] + x[idx];
  }
}

extern "C" void kernel_launch(void* const* d_in, const int* in_sizes, int n_in,
                              void* d_out, int out_size, void* d_ws, size_t ws_size,
                              hipStream_t stream) {
  const float* x      = (const float*)d_in[0];
  const float* gn_w   = (const float*)d_in[1];
  const float* gn_b   = (const float*)d_in[2];
  const float* pin_w  = (const float*)d_in[3];
  const float* pin_b  = (const float*)d_in[4];
  const float* ffln_w = (const float*)d_in[19];
  const float* ffln_b = (const float*)d_in[20];
  const float* ff_w1  = (const float*)d_in[21];
  const float* ff_b1  = (const float*)d_in[22];
  const float* ff_w2  = (const float*)d_in[23];
  const float* ff_b2  = (const float*)d_in[24];
  const float* pout_w = (const float*)d_in[25];
  const float* pout_b = (const float*)d_in[26];

  const size_t NTC = (size_t)NT * CH;  // 10,485,760
  bf16* W0 = (bf16*)d_ws;              // hs residual stream
  bf16* W1 = W0 + NTC;
  bf16* W2 = W1 + NTC;
  bf16* W3 = W2 + NTC;
  // d_out (fp32, 41.9 MB): first NTC bf16 (21 MB) = OB scratch + gnstat head;
  // upper half hosts transposed bf16 weights (4.5 MB). final_kernel
  // overwrites all of d_out at the end.
  bf16* OB = (bf16*)d_out;
  float* gnstat = (float*)d_out;
  bf16* WT = (bf16*)d_out + NTC;
  bf16* wt_pin  = WT;                   // 320x320
  bf16* wt_qkv1 = wt_pin + 102400;      // 960x320 (q|k|v rows)
  bf16* wt_wo1  = wt_qkv1 + 307200;
  bf16* wt_qkv2 = wt_wo1 + 102400;
  bf16* wt_wo2  = wt_qkv2 + 307200;
  bf16* wt_ff1  = wt_wo2 + 102400;      // 2560x320
  bf16* wt_ff2  = wt_ff1 + 819200;      // 320x1280
  bf16* wt_pout = wt_ff2 + 409600;      // 320x320

  // weight transpose descriptors (fp32 [K][N] -> bf16 [N][K])
  TDs td; int t0 = 0;
  auto add = [&](int i, const float* s, bf16* d, int K, int N) {
    td.d[i] = {s, d, K, N, t0}; t0 += (K / 32) * (N / 32);
  };
  add(0, pin_w, wt_pin, 320, 320);
  add(1, (const float*)d_in[7],  wt_qkv1,             320, 320);  // wq1
  add(2, (const float*)d_in[8],  wt_qkv1 + 102400,    320, 320);  // wk1
  add(3, (const float*)d_in[9],  wt_qkv1 + 204800,    320, 320);  // wv1
  add(4, (const float*)d_in[10], wt_wo1,              320, 320);  // wo1
  add(5, (const float*)d_in[14], wt_qkv2,             320, 320);  // wq2
  add(6, (const float*)d_in[15], wt_qkv2 + 102400,    320, 320);  // wk2
  add(7, (const float*)d_in[16], wt_qkv2 + 204800,    320, 320);  // wv2
  add(8, (const float*)d_in[17], wt_wo2,              320, 320);  // wo2
  add(9, ff_w1, wt_ff1, 320, 2560);
  add(10, ff_w2, wt_ff2, 1280, 320);
  add(11, pout_w, wt_pout, 320, 320);
  transpose_w_kernel<<<t0, 256, 0, stream>>>(td, 12);

  dim3 g_trans(32, 10, NIMG);
  dim3 g_gemm(NT / 128, 5);

  // GroupNorm -> tokens
  gn_stats_kernel<<<dim3(32, NIMG), 256, 0, stream>>>(x, gnstat);
  gn_apply_kernel<<<g_trans, 256, 0, stream>>>(x, gn_w, gn_b, gnstat, W1);
  // proj_in
  gemm_mfma_kernel<<<g_gemm, 256, 0, stream>>>(W1, wt_pin, pin_b, nullptr,
                                               W0, W0, W0, NT, CH);

  for (int blk = 0; blk < 2; ++blk) {
    const float* lnw = (const float*)d_in[5 + 7 * blk];
    const float* lnb = (const float*)d_in[6 + 7 * blk];
    const float* bo  = (const float*)d_in[11 + 7 * blk];
    bf16* wt_qkv = blk ? wt_qkv2 : wt_qkv1;
    bf16* wt_wo  = blk ? wt_wo2  : wt_wo1;

    layernorm_kernel<<<NT, 320, 0, stream>>>(W0, lnw, lnb, W1);
    to_temporal_kernel<<<NT, 320, 0, stream>>>(W1, W2);              // W2 = t (+PE)
    // fused QKV: Q->W3, K->OB, V->W1
    gemm_mfma_kernel<<<dim3(NT / 128, 15), 256, 0, stream>>>(W2, wt_qkv, nullptr, nullptr,
                                                             W3, OB, W1, NT, CH);
    attention_kernel<<<NSEQ, 256, 0, stream>>>(W3, OB, W1, W2);      // W2 = attn out
    gemm_mfma_kernel<<<g_gemm, 256, 0, stream>>>(W2, wt_wo, bo, nullptr,
                                                 W3, W3, W3, NT, CH); // o proj
    from_temporal_res_kernel<<<NT, 320, 0, stream>>>(W3, W0);        // hs += rearranged
  }

  // FF (GEGLU), M-halved so act (MH x 1280) fits in W2+W3
  layernorm_kernel<<<NT, 320, 0, stream>>>(W0, ffln_w, ffln_b, W1);
  const int MH = NT / 2;
  for (int h = 0; h < 2; ++h) {
    const bf16* Ah = W1 + (size_t)h * MH * CH;
    bf16* act = W2;  // MH*1280 elements across W2..W3
    gemm_mfma_geglu_kernel<<<dim3(MH / 128, 20), 256, 0, stream>>>(Ah, wt_ff1, ff_b1,
                                                                   act, MH, CH);
    bf16* hsh = W0 + (size_t)h * MH * CH;
    gemm_mfma_kernel<<<dim3(MH / 128, 5), 256, 0, stream>>>(act, wt_ff2, ff_b2, hsh,
                                                            hsh, hsh, hsh, MH, INNER);
  }

  // proj_out + spatial residual (fp32 out)
  gemm_mfma_kernel<<<g_gemm, 256, 0, stream>>>(W0, wt_pout, pout_b, nullptr,
                                               W1, W1, W1, NT, CH);
  final_kernel<<<g_trans, 256, 0, stream>>>(W1, x, (float*)d_out);
}

// Round 6
// 693.269 us; speedup vs baseline: 6.0792x; 1.2665x over previous
//
#include <hip/hip_runtime.h>
#include <hip/hip_bf16.h>
#include <math.h>

typedef __hip_bfloat16 bf16;
typedef __attribute__((ext_vector_type(8))) short bf16x8;   // 8 bf16 = 4 VGPRs
typedef __attribute__((ext_vector_type(4))) float f32x4;

#define NT    32768   // total tokens
#define CH    320
#define NSEQ  2048
#define FRAMES 16
#define HEADS 8
#define DHEAD 40
#define INNER 1280
#define HW    1024
#define NIMG  32

__device__ __forceinline__ float b2f(bf16 v) { return __bfloat162float(v); }
__device__ __forceinline__ bf16  f2b(float v) { return __float2bfloat16(v); }
__device__ __forceinline__ float bfbits2f(unsigned short u) {
  union { unsigned int i; float f; } x; x.i = ((unsigned int)u) << 16; return x.f;
}
__device__ __forceinline__ unsigned short f2bfbits(float f) {
  union { float f; unsigned int i; } x; x.f = f;
  return (unsigned short)((x.i + 0x7FFF + ((x.i >> 16) & 1)) >> 16);
}

// async global->LDS 16B (wave-uniform base + lane*16)
__device__ __forceinline__ void stage16(const bf16* g, bf16* l) {
  __builtin_amdgcn_global_load_lds(
      (const __attribute__((address_space(1))) void*)g,
      (__attribute__((address_space(3))) void*)l, 16, 0, 0);
}

__device__ __forceinline__ float block_reduce_sum(float v, float* sbuf) {
  int lane = threadIdx.x & 63;
  int wv   = threadIdx.x >> 6;
#pragma unroll
  for (int off = 32; off; off >>= 1) v += __shfl_down(v, off);
  __syncthreads();
  if (lane == 0) sbuf[wv] = v;
  __syncthreads();
  int nw = ((int)blockDim.x + 63) >> 6;
  float r = 0.f;
  for (int i = 0; i < nw; ++i) r += sbuf[i];
  return r;
}

// ---- weight transpose+cast: [K][N] fp32 -> [N][K] bf16, batched ----
struct TD { const float* src; bf16* dst; int K, N, t0; };
struct TDs { TD d[12]; };
__global__ __launch_bounds__(256) void transpose_w_kernel(TDs td, int ndesc) {
  __shared__ float tile[32][33];
  int bt = blockIdx.x;
  int mi = 0;
  for (int i = 1; i < 12; ++i) if (i < ndesc && bt >= td.d[i].t0) mi = i;
  TD e = td.d[mi];
  int lt = bt - e.t0;
  int ntx = e.N >> 5;
  int kt = lt / ntx, nt = lt - kt * ntx;
#pragma unroll
  for (int q = 0; q < 4; ++q) {
    int idx = threadIdx.x + q * 256; int r = idx >> 5, c = idx & 31;
    tile[r][c] = e.src[(size_t)(kt * 32 + r) * e.N + nt * 32 + c];
  }
  __syncthreads();
#pragma unroll
  for (int q = 0; q < 4; ++q) {
    int idx = threadIdx.x + q * 256; int r = idx >> 5, c = idx & 31;
    e.dst[(size_t)(nt * 32 + r) * e.K + kt * 32 + c] = f2b(tile[c][r]);
  }
}

// ---- MFMA GEMM: C = A[M,K] @ BT[N,K]^T (+bias) (+res) ----
// BM=128 BN=64 BK=64; 4 waves (2x2), wave tile 64x32. Output width 320.
// rowmap=1: output (and res) row goes through temporal->spatial scatter.
__global__ __launch_bounds__(256) void gemm_mfma_kernel(
    const bf16* __restrict__ A, const bf16* __restrict__ BT,
    const float* __restrict__ bias, const bf16* res,
    bf16* C0, bf16* C1, bf16* C2, int M, int K, int rowmap) {
  __shared__ __align__(16) bf16 sA[128 * 64];
  __shared__ __align__(16) bf16 sB[64 * 64];
  int tid = threadIdx.x, lane = tid & 63, w = tid >> 6;
  int wm = w >> 1, wn = w & 1;
  int m0 = blockIdx.x * 128, n0 = blockIdx.y * 64;
  int which = n0 / 320;
  int ncol0 = n0 - which * 320;
  bf16* C = which == 0 ? C0 : (which == 1 ? C1 : C2);
  f32x4 acc[4][2];
#pragma unroll
  for (int i = 0; i < 4; ++i)
#pragma unroll
    for (int j = 0; j < 2; ++j) acc[i][j] = (f32x4){0.f, 0.f, 0.f, 0.f};

  int lr = lane >> 3;
  int cg = (lane & 7) ^ lr;
  for (int k0 = 0; k0 < K; k0 += 64) {
#pragma unroll
    for (int s = 0; s < 4; ++s) {
      int tA = w * 4 + s;
      int row = tA * 8 + lr;
      stage16(A + (size_t)(m0 + row) * K + k0 + cg * 8, sA + tA * 512);
    }
#pragma unroll
    for (int s = 0; s < 2; ++s) {
      int tB = w * 2 + s;
      int row = tB * 8 + lr;
      stage16(BT + (size_t)(n0 + row) * K + k0 + cg * 8, sB + tB * 512);
    }
    __syncthreads();
#pragma unroll
    for (int kk = 0; kk < 2; ++kk) {
      bf16x8 a[4], b[2];
      int cc = kk * 4 + (lane >> 4);
#pragma unroll
      for (int i = 0; i < 4; ++i) {
        int r = wm * 64 + i * 16 + (lane & 15);
        a[i] = *(const bf16x8*)(sA + r * 64 + ((cc ^ (r & 7)) * 8));
      }
#pragma unroll
      for (int j = 0; j < 2; ++j) {
        int n = wn * 32 + j * 16 + (lane & 15);
        b[j] = *(const bf16x8*)(sB + n * 64 + ((cc ^ (n & 7)) * 8));
      }
#pragma unroll
      for (int i = 0; i < 4; ++i)
#pragma unroll
        for (int j = 0; j < 2; ++j)
          acc[i][j] = __builtin_amdgcn_mfma_f32_16x16x32_bf16(a[i], b[j], acc[i][j], 0, 0, 0);
    }
    __syncthreads();
  }
#pragma unroll
  for (int i = 0; i < 4; ++i)
#pragma unroll
    for (int j = 0; j < 2; ++j) {
      int row0 = m0 + wm * 64 + i * 16 + (lane >> 4) * 4;
      int col  = ncol0 + wn * 32 + j * 16 + (lane & 15);
      float bv = bias ? bias[col] : 0.f;
#pragma unroll
      for (int rg = 0; rg < 4; ++rg) {
        int r = row0 + rg;
        if (rowmap) {  // temporal row -> spatial row
          int n = r >> 4, fi = r & 15, bb = n >> 10, dd = n & 1023;
          r = ((bb << 4) + fi) * 1024 + dd;
        }
        size_t idx = (size_t)r * 320 + col;
        float v = acc[i][j][rg] + bv;
        if (res) v += b2f(res[idx]);
        C[idx] = f2b(v);
      }
    }
}

// ---- MFMA GEGLU GEMM ----
__global__ __launch_bounds__(256) void gemm_mfma_geglu_kernel(
    const bf16* __restrict__ A, const bf16* __restrict__ BT,
    const float* __restrict__ b1, bf16* __restrict__ act, int M, int K) {
  __shared__ __align__(16) bf16 sA[128 * 64];
  __shared__ __align__(16) bf16 sBa[64 * 64];
  __shared__ __align__(16) bf16 sBg[64 * 64];
  int tid = threadIdx.x, lane = tid & 63, w = tid >> 6;
  int wm = w >> 1, wn = w & 1;
  int m0 = blockIdx.x * 128, n0 = blockIdx.y * 64;
  f32x4 aa[4][2], ag[4][2];
#pragma unroll
  for (int i = 0; i < 4; ++i)
#pragma unroll
    for (int j = 0; j < 2; ++j) {
      aa[i][j] = (f32x4){0.f, 0.f, 0.f, 0.f};
      ag[i][j] = (f32x4){0.f, 0.f, 0.f, 0.f};
    }
  int lr = lane >> 3;
  int cg = (lane & 7) ^ lr;
  for (int k0 = 0; k0 < K; k0 += 64) {
#pragma unroll
    for (int s = 0; s < 4; ++s) {
      int tA = w * 4 + s;
      int row = tA * 8 + lr;
      stage16(A + (size_t)(m0 + row) * K + k0 + cg * 8, sA + tA * 512);
    }
#pragma unroll
    for (int s = 0; s < 2; ++s) {
      int tB = w * 2 + s;
      int row = tB * 8 + lr;
      stage16(BT + (size_t)(n0 + row) * K + k0 + cg * 8, sBa + tB * 512);
      stage16(BT + (size_t)(1280 + n0 + row) * K + k0 + cg * 8, sBg + tB * 512);
    }
    __syncthreads();
#pragma unroll
    for (int kk = 0; kk < 2; ++kk) {
      bf16x8 a[4], ba[2], bg[2];
      int cc = kk * 4 + (lane >> 4);
#pragma unroll
      for (int i = 0; i < 4; ++i) {
        int r = wm * 64 + i * 16 + (lane & 15);
        a[i] = *(const bf16x8*)(sA + r * 64 + ((cc ^ (r & 7)) * 8));
      }
#pragma unroll
      for (int j = 0; j < 2; ++j) {
        int n = wn * 32 + j * 16 + (lane & 15);
        ba[j] = *(const bf16x8*)(sBa + n * 64 + ((cc ^ (n & 7)) * 8));
        bg[j] = *(const bf16x8*)(sBg + n * 64 + ((cc ^ (n & 7)) * 8));
      }
#pragma unroll
      for (int i = 0; i < 4; ++i)
#pragma unroll
        for (int j = 0; j < 2; ++j) {
          aa[i][j] = __builtin_amdgcn_mfma_f32_16x16x32_bf16(a[i], ba[j], aa[i][j], 0, 0, 0);
          ag[i][j] = __builtin_amdgcn_mfma_f32_16x16x32_bf16(a[i], bg[j], ag[i][j], 0, 0, 0);
        }
    }
    __syncthreads();
  }
#pragma unroll
  for (int i = 0; i < 4; ++i)
#pragma unroll
    for (int j = 0; j < 2; ++j) {
      int row0 = m0 + wm * 64 + i * 16 + (lane >> 4) * 4;
      int col  = n0 + wn * 32 + j * 16 + (lane & 15);
      float bva = b1[col], bvg = b1[1280 + col];
#pragma unroll
      for (int rg = 0; rg < 4; ++rg) {
        float av = aa[i][j][rg] + bva;
        float gv = ag[i][j][rg] + bvg;
        float gelu = 0.5f * gv * (1.0f + erff(gv * 0.70710678118654752f));
        act[(size_t)(row0 + rg) * 1280 + col] = f2b(av * gelu);
      }
    }
}

// ---- GroupNorm stats ----
__global__ __launch_bounds__(256) void gn_stats_kernel(const float* __restrict__ x,
                                                       float* __restrict__ stat) {
  __shared__ float sbuf[8];
  int g  = blockIdx.x;
  int im = blockIdx.y;
  const float* base = x + ((size_t)im * CH + (size_t)g * 10) * HW;
  float s = 0.f, s2 = 0.f;
  for (int i = threadIdx.x; i < 10 * HW; i += 256) {
    float v = base[i];
    s += v; s2 += v * v;
  }
  s  = block_reduce_sum(s, sbuf);
  s2 = block_reduce_sum(s2, sbuf);
  if (threadIdx.x == 0) {
    float mean = s * (1.f / 10240.f);
    float var  = s2 * (1.f / 10240.f) - mean * mean;
    stat[(im * 32 + g) * 2 + 0] = mean;
    stat[(im * 32 + g) * 2 + 1] = rsqrtf(var + 1e-6f);
  }
}

// ---- GN apply + transpose -> tokens ----
__global__ __launch_bounds__(256) void gn_apply_kernel(const float* __restrict__ x,
                                                       const float* __restrict__ gw,
                                                       const float* __restrict__ gb,
                                                       const float* __restrict__ stat,
                                                       bf16* __restrict__ xn) {
  __shared__ float tile[32][33];
  int st = blockIdx.x, ct = blockIdx.y, im = blockIdx.z;
  int c0 = ct * 32, s0 = st * 32;
  for (int t = threadIdx.x; t < 1024; t += 256) {
    int i = t >> 5, j = t & 31;
    int c = c0 + i;
    int g = c / 10;
    float mean = stat[(im * 32 + g) * 2 + 0];
    float rstd = stat[(im * 32 + g) * 2 + 1];
    tile[i][j] = (x[((size_t)(im * CH + c) << 10) + s0 + j] - mean) * rstd * gw[c] + gb[c];
  }
  __syncthreads();
  for (int t = threadIdx.x; t < 1024; t += 256) {
    int i = t >> 5, j = t & 31;
    xn[((size_t)(im * HW + s0 + i)) * CH + c0 + j] = f2b(tile[j][i]);
  }
}

// ---- LayerNorm (plain, for FF) ----
__global__ __launch_bounds__(320) void layernorm_kernel(const bf16* __restrict__ in,
                                                        const float* __restrict__ w,
                                                        const float* __restrict__ b,
                                                        bf16* __restrict__ out) {
  __shared__ float sbuf[8];
  int row = blockIdx.x;
  int c = threadIdx.x;
  size_t idx = (size_t)row * CH + c;
  float x = b2f(in[idx]);
  float mean = block_reduce_sum(x, sbuf) * (1.f / 320.f);
  float d = x - mean;
  float var = block_reduce_sum(d * d, sbuf) * (1.f / 320.f);
  float rstd = rsqrtf(var + 1e-5f);
  out[idx] = f2b(d * rstd * w[c] + b[c]);
}

// ---- fused LayerNorm + (b f) d c -> (b d) f c rearrange + temporal PE ----
__global__ __launch_bounds__(320) void ln_temporal_kernel(const bf16* __restrict__ in,
                                                          const float* __restrict__ w,
                                                          const float* __restrict__ b,
                                                          bf16* __restrict__ tout) {
  __shared__ float sbuf[8];
  int row = blockIdx.x;             // spatial-order row
  int c = threadIdx.x;
  size_t idx = (size_t)row * CH + c;
  float x = b2f(in[idx]);
  float mean = block_reduce_sum(x, sbuf) * (1.f / 320.f);
  float dv = x - mean;
  float var = block_reduce_sum(dv * dv, sbuf) * (1.f / 320.f);
  float rstd = rsqrtf(var + 1e-5f);
  int img = row >> 10, dd = row & 1023, bb = img >> 4, fi = img & 15;
  int trow = (((bb << 10) + dd) << 4) + fi;
  float arg = (float)fi * expf((float)(c & ~1) * -0.028782313662425575f);
  float pe = (c & 1) ? cosf(arg) : sinf(arg);
  tout[(size_t)trow * CH + c] = f2b(dv * rstd * w[c] + b[c] + pe);
}

// ---- temporal attention: one block per sequence, conflict-aware fp32 LDS ----
#define AROW 324   // row stride in floats: 324%32=4 (bank-spread), 16B-aligned
__global__ __launch_bounds__(256) void attention_kernel(const bf16* __restrict__ Q,
                                                        const bf16* __restrict__ K,
                                                        const bf16* __restrict__ V,
                                                        bf16* __restrict__ O) {
  __shared__ float q[16 * AROW];
  __shared__ float k[16 * AROW];
  __shared__ float v[16 * AROW];
  __shared__ float sc[HEADS * 16 * 16];
  const float SCALE = 0.15811388300841897f;
  int tid = threadIdx.x;
  int n = blockIdx.x;
  size_t base = (size_t)n * FRAMES * CH;
  // stage Q,K,V: 4-bf16 chunks, 80 chunks per 320-row
  for (int j = tid; j < 1280; j += 256) {
    int row = j / 80, off = (j - row * 80) * 4;
    int src = row * 320 + off;
    ushort4 uq = *(const ushort4*)(Q + base + src);
    ushort4 uk = *(const ushort4*)(K + base + src);
    ushort4 uv = *(const ushort4*)(V + base + src);
    float* qd = &q[row * AROW + off];
    float* kd = &k[row * AROW + off];
    float* vd = &v[row * AROW + off];
    qd[0] = bfbits2f(uq.x) * SCALE; qd[1] = bfbits2f(uq.y) * SCALE;
    qd[2] = bfbits2f(uq.z) * SCALE; qd[3] = bfbits2f(uq.w) * SCALE;
    kd[0] = bfbits2f(uk.x); kd[1] = bfbits2f(uk.y);
    kd[2] = bfbits2f(uk.z); kd[3] = bfbits2f(uk.w);
    vd[0] = bfbits2f(uv.x); vd[1] = bfbits2f(uv.y);
    vd[2] = bfbits2f(uv.z); vd[3] = bfbits2f(uv.w);
  }
  __syncthreads();
  // scores: thread -> (h, qf, kf-group of 8); float4 over d
  {
    int h = tid >> 5, sub = tid & 31, qf = sub >> 1, kfg = sub & 1;
    const float* qrow = &q[qf * AROW + h * DHEAD];
    float s[8] = {0.f, 0.f, 0.f, 0.f, 0.f, 0.f, 0.f, 0.f};
#pragma unroll
    for (int d4 = 0; d4 < 10; ++d4) {
      float4 qv = *(const float4*)(qrow + d4 * 4);
#pragma unroll
      for (int i = 0; i < 8; ++i) {
        const float* krow = &k[(kfg * 8 + i) * AROW + h * DHEAD];
        float4 kv = *(const float4*)(krow + d4 * 4);
        s[i] += qv.x * kv.x + qv.y * kv.y + qv.z * kv.z + qv.w * kv.w;
      }
    }
    float* dst = &sc[(h * 16 + qf) * 16 + kfg * 8];
#pragma unroll
    for (int i = 0; i < 8; ++i) dst[i] = s[i];
  }
  __syncthreads();
  if (tid < 128) {   // softmax per (h,qf) row
    float* r = &sc[tid * 16];
    float mx = r[0];
#pragma unroll
    for (int i = 1; i < 16; ++i) mx = fmaxf(mx, r[i]);
    float sum = 0.f;
#pragma unroll
    for (int i = 0; i < 16; ++i) { float e = expf(r[i] - mx); r[i] = e; sum += e; }
    float inv = 1.0f / sum;
#pragma unroll
    for (int i = 0; i < 16; ++i) r[i] *= inv;
  }
  __syncthreads();
  // PV: 1280 float4 outputs (16 qf x 80 c4)
  for (int g = tid; g < 1280; g += 256) {
    int qf = g / 80, c4 = g - qf * 80;
    int h = c4 / 10;
    const float* p = &sc[(h * 16 + qf) * 16];
    float4 o = {0.f, 0.f, 0.f, 0.f};
#pragma unroll
    for (int kf = 0; kf < 16; ++kf) {
      float pv = p[kf];
      float4 vv = *(const float4*)&v[kf * AROW + c4 * 4];
      o.x += pv * vv.x; o.y += pv * vv.y; o.z += pv * vv.z; o.w += pv * vv.w;
    }
    ushort4 u;
    u.x = f2bfbits(o.x); u.y = f2bfbits(o.y);
    u.z = f2bfbits(o.z); u.w = f2bfbits(o.w);
    *(ushort4*)(O + base + qf * 320 + c4 * 4) = u;
  }
}

// ---- final: tokens -> [img][c][s] + fp32 spatial residual; fp32 out ----
__global__ __launch_bounds__(256) void final_kernel(const bf16* __restrict__ proj,
                                                    const float* __restrict__ x,
                                                    float* __restrict__ out) {
  __shared__ float tile[32][33];
  int st = blockIdx.x, ct = blockIdx.y, im = blockIdx.z;
  int c0 = ct * 32, s0 = st * 32;
  for (int t = threadIdx.x; t < 1024; t += 256) {
    int i = t >> 5, j = t & 31;
    tile[i][j] = b2f(proj[((size_t)(im * HW + s0 + i)) * CH + c0 + j]);
  }
  __syncthreads();
  for (int t = threadIdx.x; t < 1024; t += 256) {
    int i = t >> 5, j = t & 31;
    size_t idx = ((size_t)(im * CH + c0 + i) << 10) + s0 + j;
    out[idx] = tile[j][i] + x[idx];
  }
}

extern "C" void kernel_launch(void* const* d_in, const int* in_sizes, int n_in,
                              void* d_out, int out_size, void* d_ws, size_t ws_size,
                              hipStream_t stream) {
  const float* x      = (const float*)d_in[0];
  const float* gn_w   = (const float*)d_in[1];
  const float* gn_b   = (const float*)d_in[2];
  const float* pin_w  = (const float*)d_in[3];
  const float* pin_b  = (const float*)d_in[4];
  const float* ffln_w = (const float*)d_in[19];
  const float* ffln_b = (const float*)d_in[20];
  const float* ff_w1  = (const float*)d_in[21];
  const float* ff_b1  = (const float*)d_in[22];
  const float* ff_w2  = (const float*)d_in[23];
  const float* ff_b2  = (const float*)d_in[24];
  const float* pout_w = (const float*)d_in[25];
  const float* pout_b = (const float*)d_in[26];

  const size_t NTC = (size_t)NT * CH;
  bf16* W0 = (bf16*)d_ws;              // hs residual stream (spatial token order)
  bf16* W1 = W0 + NTC;
  bf16* W2 = W1 + NTC;
  bf16* W3 = W2 + NTC;
  bf16* OB = (bf16*)d_out;             // scratch until final_kernel
  float* gnstat = (float*)d_out;
  bf16* WT = (bf16*)d_out + NTC;       // transposed weights region
  bf16* wt_pin  = WT;
  bf16* wt_qkv1 = wt_pin + 102400;
  bf16* wt_wo1  = wt_qkv1 + 307200;
  bf16* wt_qkv2 = wt_wo1 + 102400;
  bf16* wt_wo2  = wt_qkv2 + 307200;
  bf16* wt_ff1  = wt_wo2 + 102400;
  bf16* wt_ff2  = wt_ff1 + 819200;
  bf16* wt_pout = wt_ff2 + 409600;

  TDs td; int t0 = 0;
  auto add = [&](int i, const float* s, bf16* d, int K, int N) {
    td.d[i] = {s, d, K, N, t0}; t0 += (K / 32) * (N / 32);
  };
  add(0, pin_w, wt_pin, 320, 320);
  add(1, (const float*)d_in[7],  wt_qkv1,          320, 320);
  add(2, (const float*)d_in[8],  wt_qkv1 + 102400, 320, 320);
  add(3, (const float*)d_in[9],  wt_qkv1 + 204800, 320, 320);
  add(4, (const float*)d_in[10], wt_wo1,           320, 320);
  add(5, (const float*)d_in[14], wt_qkv2,          320, 320);
  add(6, (const float*)d_in[15], wt_qkv2 + 102400, 320, 320);
  add(7, (const float*)d_in[16], wt_qkv2 + 204800, 320, 320);
  add(8, (const float*)d_in[17], wt_wo2,           320, 320);
  add(9, ff_w1, wt_ff1, 320, 2560);
  add(10, ff_w2, wt_ff2, 1280, 320);
  add(11, pout_w, wt_pout, 320, 320);
  transpose_w_kernel<<<t0, 256, 0, stream>>>(td, 12);

  dim3 g_trans(32, 10, NIMG);
  dim3 g_gemm(NT / 128, 5);

  gn_stats_kernel<<<dim3(32, NIMG), 256, 0, stream>>>(x, gnstat);
  gn_apply_kernel<<<g_trans, 256, 0, stream>>>(x, gn_w, gn_b, gnstat, W1);
  gemm_mfma_kernel<<<g_gemm, 256, 0, stream>>>(W1, wt_pin, pin_b, nullptr,
                                               W0, W0, W0, NT, CH, 0);

  for (int blk = 0; blk < 2; ++blk) {
    const float* lnw = (const float*)d_in[5 + 7 * blk];
    const float* lnb = (const float*)d_in[6 + 7 * blk];
    const float* bo  = (const float*)d_in[11 + 7 * blk];
    bf16* wt_qkv = blk ? wt_qkv2 : wt_qkv1;
    bf16* wt_wo  = blk ? wt_wo2  : wt_wo1;

    // LN + rearrange-to-temporal + PE in one pass
    ln_temporal_kernel<<<NT, 320, 0, stream>>>(W0, lnw, lnb, W2);
    // fused QKV: Q->W3, K->OB, V->W1 (temporal order)
    gemm_mfma_kernel<<<dim3(NT / 128, 15), 256, 0, stream>>>(W2, wt_qkv, nullptr, nullptr,
                                                             W3, OB, W1, NT, CH, 0);
    attention_kernel<<<NSEQ, 256, 0, stream>>>(W3, OB, W1, W2);
    // o-proj with fused rearrange-to-spatial + residual add into W0
    gemm_mfma_kernel<<<g_gemm, 256, 0, stream>>>(W2, wt_wo, bo, W0,
                                                 W0, W0, W0, NT, CH, 1);
  }

  layernorm_kernel<<<NT, 320, 0, stream>>>(W0, ffln_w, ffln_b, W1);
  const int MH = NT / 2;
  for (int h = 0; h < 2; ++h) {
    const bf16* Ah = W1 + (size_t)h * MH * CH;
    bf16* act = W2;
    gemm_mfma_geglu_kernel<<<dim3(MH / 128, 20), 256, 0, stream>>>(Ah, wt_ff1, ff_b1,
                                                                   act, MH, CH);
    bf16* hsh = W0 + (size_t)h * MH * CH;
    gemm_mfma_kernel<<<dim3(MH / 128, 5), 256, 0, stream>>>(act, wt_ff2, ff_b2, hsh,
                                                            hsh, hsh, hsh, MH, INNER, 0);
  }

  gemm_mfma_kernel<<<g_gemm, 256, 0, stream>>>(W0, wt_pout, pout_b, nullptr,
                                               W1, W1, W1, NT, CH, 0);
  final_kernel<<<g_trans, 256, 0, stream>>>(W1, x, (float*)d_out);
}

// Round 7
// 595.740 us; speedup vs baseline: 7.0744x; 1.1637x over previous
//
#include <hip/hip_runtime.h>
#include <hip/hip_bf16.h>
#include <math.h>

typedef __hip_bfloat16 bf16;
typedef __attribute__((ext_vector_type(8))) short bf16x8;   // 8 bf16 = 4 VGPRs
typedef __attribute__((ext_vector_type(4))) float f32x4;

#define NT    32768   // total tokens
#define CH    320
#define NSEQ  2048
#define FRAMES 16
#define HEADS 8
#define DHEAD 40
#define INNER 1280
#define HW    1024
#define NIMG  32

__device__ __forceinline__ float b2f(bf16 v) { return __bfloat162float(v); }
__device__ __forceinline__ bf16  f2b(float v) { return __float2bfloat16(v); }
__device__ __forceinline__ float bfbits2f(unsigned short u) {
  union { unsigned int i; float f; } x; x.i = ((unsigned int)u) << 16; return x.f;
}
__device__ __forceinline__ unsigned short f2bfbits(float f) {
  union { float f; unsigned int i; } x; x.f = f;
  return (unsigned short)((x.i + 0x7FFF + ((x.i >> 16) & 1)) >> 16);
}

// async global->LDS 16B (wave-uniform base + lane*16)
__device__ __forceinline__ void stage16(const bf16* g, bf16* l) {
  __builtin_amdgcn_global_load_lds(
      (const __attribute__((address_space(1))) void*)g,
      (__attribute__((address_space(3))) void*)l, 16, 0, 0);
}

__device__ __forceinline__ float block_reduce_sum(float v, float* sbuf) {
  int lane = threadIdx.x & 63;
  int wv   = threadIdx.x >> 6;
#pragma unroll
  for (int off = 32; off; off >>= 1) v += __shfl_down(v, off);
  __syncthreads();
  if (lane == 0) sbuf[wv] = v;
  __syncthreads();
  int nw = ((int)blockDim.x + 63) >> 6;
  float r = 0.f;
  for (int i = 0; i < nw; ++i) r += sbuf[i];
  return r;
}

// ---- weight transpose+cast: [K][N] fp32 -> [N][K] bf16, batched ----
struct TD { const float* src; bf16* dst; int K, N, t0; };
struct TDs { TD d[12]; };
__global__ __launch_bounds__(256) void transpose_w_kernel(TDs td, int ndesc) {
  __shared__ float tile[32][33];
  int bt = blockIdx.x;
  int mi = 0;
  for (int i = 1; i < 12; ++i) if (i < ndesc && bt >= td.d[i].t0) mi = i;
  TD e = td.d[mi];
  int lt = bt - e.t0;
  int ntx = e.N >> 5;
  int kt = lt / ntx, nt = lt - kt * ntx;
#pragma unroll
  for (int q = 0; q < 4; ++q) {
    int idx = threadIdx.x + q * 256; int r = idx >> 5, c = idx & 31;
    tile[r][c] = e.src[(size_t)(kt * 32 + r) * e.N + nt * 32 + c];
  }
  __syncthreads();
#pragma unroll
  for (int q = 0; q < 4; ++q) {
    int idx = threadIdx.x + q * 256; int r = idx >> 5, c = idx & 31;
    e.dst[(size_t)(nt * 32 + r) * e.K + kt * 32 + c] = f2b(tile[c][r]);
  }
}

// ---- temporal positional-encoding table: pe[fi][c], 16x320 fp32 ----
__global__ __launch_bounds__(256) void pe_table_kernel(float* __restrict__ petab) {
  int i = blockIdx.x * 256 + threadIdx.x;
  if (i < 16 * CH) {
    int fi = i / CH, c = i - fi * CH;
    float arg = (float)fi * expf((float)(c & ~1) * -0.028782313662425575f);
    petab[i] = (c & 1) ? cosf(arg) : sinf(arg);
  }
}

// ---- wave-per-row LayerNorm; mode 0: plain; mode 1: +PE, temporal scatter ----
__global__ __launch_bounds__(256) void ln_fused_kernel(const bf16* __restrict__ in,
                                                       const float* __restrict__ w,
                                                       const float* __restrict__ b,
                                                       bf16* __restrict__ out,
                                                       const float* __restrict__ petab,
                                                       int mode) {
  int wv = threadIdx.x >> 6, lane = threadIdx.x & 63;
  int row = blockIdx.x * 4 + wv;
  size_t base = (size_t)row * CH;
  float v[5];
  float s = 0.f;
#pragma unroll
  for (int j = 0; j < 5; ++j) {
    v[j] = b2f(in[base + lane + 64 * j]);
    s += v[j];
  }
#pragma unroll
  for (int off = 32; off; off >>= 1) s += __shfl_down(s, off);
  float mean = __shfl(s, 0) * (1.f / 320.f);
  float s2 = 0.f;
#pragma unroll
  for (int j = 0; j < 5; ++j) { float d = v[j] - mean; s2 += d * d; }
#pragma unroll
  for (int off = 32; off; off >>= 1) s2 += __shfl_down(s2, off);
  float rstd = rsqrtf(__shfl(s2, 0) * (1.f / 320.f) + 1e-5f);
  size_t obase = base;
  const float* pe = nullptr;
  if (mode) {
    int img = row >> 10, dd = row & 1023, bb = img >> 4, fi = img & 15;
    int trow = (((bb << 10) + dd) << 4) + fi;
    obase = (size_t)trow * CH;
    pe = petab + fi * CH;
  }
#pragma unroll
  for (int j = 0; j < 5; ++j) {
    int c = lane + 64 * j;
    float o = (v[j] - mean) * rstd * w[c] + b[c];
    if (mode) o += pe[c];
    out[obase + c] = f2b(o);
  }
}

// ---- MFMA GEMM: C = A[M,K] @ BT[N,K]^T (+bias) (+res) ----
// BM=128 BN=64 BK=64; 4 waves (2x2), wave tile 64x32. Output width 320.
// rowmap=1: output (and res) row goes through temporal->spatial scatter.
__global__ __launch_bounds__(256) void gemm_mfma_kernel(
    const bf16* __restrict__ A, const bf16* __restrict__ BT,
    const float* __restrict__ bias, const bf16* res,
    bf16* C0, bf16* C1, bf16* C2, int M, int K, int rowmap) {
  __shared__ __align__(16) bf16 sA[128 * 64];
  __shared__ __align__(16) bf16 sB[64 * 64];
  int tid = threadIdx.x, lane = tid & 63, w = tid >> 6;
  int wm = w >> 1, wn = w & 1;
  int m0 = blockIdx.x * 128, n0 = blockIdx.y * 64;
  int which = n0 / 320;
  int ncol0 = n0 - which * 320;
  bf16* C = which == 0 ? C0 : (which == 1 ? C1 : C2);
  f32x4 acc[4][2];
#pragma unroll
  for (int i = 0; i < 4; ++i)
#pragma unroll
    for (int j = 0; j < 2; ++j) acc[i][j] = (f32x4){0.f, 0.f, 0.f, 0.f};

  int lr = lane >> 3;
  int cg = (lane & 7) ^ lr;
  for (int k0 = 0; k0 < K; k0 += 64) {
#pragma unroll
    for (int s = 0; s < 4; ++s) {
      int tA = w * 4 + s;
      int row = tA * 8 + lr;
      stage16(A + (size_t)(m0 + row) * K + k0 + cg * 8, sA + tA * 512);
    }
#pragma unroll
    for (int s = 0; s < 2; ++s) {
      int tB = w * 2 + s;
      int row = tB * 8 + lr;
      stage16(BT + (size_t)(n0 + row) * K + k0 + cg * 8, sB + tB * 512);
    }
    __syncthreads();
#pragma unroll
    for (int kk = 0; kk < 2; ++kk) {
      bf16x8 a[4], b[2];
      int cc = kk * 4 + (lane >> 4);
#pragma unroll
      for (int i = 0; i < 4; ++i) {
        int r = wm * 64 + i * 16 + (lane & 15);
        a[i] = *(const bf16x8*)(sA + r * 64 + ((cc ^ (r & 7)) * 8));
      }
#pragma unroll
      for (int j = 0; j < 2; ++j) {
        int n = wn * 32 + j * 16 + (lane & 15);
        b[j] = *(const bf16x8*)(sB + n * 64 + ((cc ^ (n & 7)) * 8));
      }
#pragma unroll
      for (int i = 0; i < 4; ++i)
#pragma unroll
        for (int j = 0; j < 2; ++j)
          acc[i][j] = __builtin_amdgcn_mfma_f32_16x16x32_bf16(a[i], b[j], acc[i][j], 0, 0, 0);
    }
    __syncthreads();
  }
#pragma unroll
  for (int i = 0; i < 4; ++i)
#pragma unroll
    for (int j = 0; j < 2; ++j) {
      int row0 = m0 + wm * 64 + i * 16 + (lane >> 4) * 4;
      int col  = ncol0 + wn * 32 + j * 16 + (lane & 15);
      float bv = bias ? bias[col] : 0.f;
#pragma unroll
      for (int rg = 0; rg < 4; ++rg) {
        int r = row0 + rg;
        if (rowmap) {  // temporal row -> spatial row
          int n = r >> 4, fi = r & 15, bb = n >> 10, dd = n & 1023;
          r = ((bb << 4) + fi) * 1024 + dd;
        }
        size_t idx = (size_t)r * 320 + col;
        float v = acc[i][j][rg] + bv;
        if (res) v += b2f(res[idx]);
        C[idx] = f2b(v);
      }
    }
}

// ---- MFMA GEGLU GEMM ----
__global__ __launch_bounds__(256) void gemm_mfma_geglu_kernel(
    const bf16* __restrict__ A, const bf16* __restrict__ BT,
    const float* __restrict__ b1, bf16* __restrict__ act, int M, int K) {
  __shared__ __align__(16) bf16 sA[128 * 64];
  __shared__ __align__(16) bf16 sBa[64 * 64];
  __shared__ __align__(16) bf16 sBg[64 * 64];
  int tid = threadIdx.x, lane = tid & 63, w = tid >> 6;
  int wm = w >> 1, wn = w & 1;
  int m0 = blockIdx.x * 128, n0 = blockIdx.y * 64;
  f32x4 aa[4][2], ag[4][2];
#pragma unroll
  for (int i = 0; i < 4; ++i)
#pragma unroll
    for (int j = 0; j < 2; ++j) {
      aa[i][j] = (f32x4){0.f, 0.f, 0.f, 0.f};
      ag[i][j] = (f32x4){0.f, 0.f, 0.f, 0.f};
    }
  int lr = lane >> 3;
  int cg = (lane & 7) ^ lr;
  for (int k0 = 0; k0 < K; k0 += 64) {
#pragma unroll
    for (int s = 0; s < 4; ++s) {
      int tA = w * 4 + s;
      int row = tA * 8 + lr;
      stage16(A + (size_t)(m0 + row) * K + k0 + cg * 8, sA + tA * 512);
    }
#pragma unroll
    for (int s = 0; s < 2; ++s) {
      int tB = w * 2 + s;
      int row = tB * 8 + lr;
      stage16(BT + (size_t)(n0 + row) * K + k0 + cg * 8, sBa + tB * 512);
      stage16(BT + (size_t)(1280 + n0 + row) * K + k0 + cg * 8, sBg + tB * 512);
    }
    __syncthreads();
#pragma unroll
    for (int kk = 0; kk < 2; ++kk) {
      bf16x8 a[4], ba[2], bg[2];
      int cc = kk * 4 + (lane >> 4);
#pragma unroll
      for (int i = 0; i < 4; ++i) {
        int r = wm * 64 + i * 16 + (lane & 15);
        a[i] = *(const bf16x8*)(sA + r * 64 + ((cc ^ (r & 7)) * 8));
      }
#pragma unroll
      for (int j = 0; j < 2; ++j) {
        int n = wn * 32 + j * 16 + (lane & 15);
        ba[j] = *(const bf16x8*)(sBa + n * 64 + ((cc ^ (n & 7)) * 8));
        bg[j] = *(const bf16x8*)(sBg + n * 64 + ((cc ^ (n & 7)) * 8));
      }
#pragma unroll
      for (int i = 0; i < 4; ++i)
#pragma unroll
        for (int j = 0; j < 2; ++j) {
          aa[i][j] = __builtin_amdgcn_mfma_f32_16x16x32_bf16(a[i], ba[j], aa[i][j], 0, 0, 0);
          ag[i][j] = __builtin_amdgcn_mfma_f32_16x16x32_bf16(a[i], bg[j], ag[i][j], 0, 0, 0);
        }
    }
    __syncthreads();
  }
#pragma unroll
  for (int i = 0; i < 4; ++i)
#pragma unroll
    for (int j = 0; j < 2; ++j) {
      int row0 = m0 + wm * 64 + i * 16 + (lane >> 4) * 4;
      int col  = n0 + wn * 32 + j * 16 + (lane & 15);
      float bva = b1[col], bvg = b1[1280 + col];
#pragma unroll
      for (int rg = 0; rg < 4; ++rg) {
        float av = aa[i][j][rg] + bva;
        float gv = ag[i][j][rg] + bvg;
        float gelu = 0.5f * gv * (1.0f + erff(gv * 0.70710678118654752f));
        act[(size_t)(row0 + rg) * 1280 + col] = f2b(av * gelu);
      }
    }
}

// ---- GroupNorm stats ----
__global__ __launch_bounds__(256) void gn_stats_kernel(const float* __restrict__ x,
                                                       float* __restrict__ stat) {
  __shared__ float sbuf[8];
  int g  = blockIdx.x;
  int im = blockIdx.y;
  const float* base = x + ((size_t)im * CH + (size_t)g * 10) * HW;
  float s = 0.f, s2 = 0.f;
  for (int i = threadIdx.x; i < 10 * HW; i += 256) {
    float v = base[i];
    s += v; s2 += v * v;
  }
  s  = block_reduce_sum(s, sbuf);
  s2 = block_reduce_sum(s2, sbuf);
  if (threadIdx.x == 0) {
    float mean = s * (1.f / 10240.f);
    float var  = s2 * (1.f / 10240.f) - mean * mean;
    stat[(im * 32 + g) * 2 + 0] = mean;
    stat[(im * 32 + g) * 2 + 1] = rsqrtf(var + 1e-6f);
  }
}

// ---- GN apply + transpose -> tokens ----
__global__ __launch_bounds__(256) void gn_apply_kernel(const float* __restrict__ x,
                                                       const float* __restrict__ gw,
                                                       const float* __restrict__ gb,
                                                       const float* __restrict__ stat,
                                                       bf16* __restrict__ xn) {
  __shared__ float tile[32][33];
  int st = blockIdx.x, ct = blockIdx.y, im = blockIdx.z;
  int c0 = ct * 32, s0 = st * 32;
  for (int t = threadIdx.x; t < 1024; t += 256) {
    int i = t >> 5, j = t & 31;
    int c = c0 + i;
    int g = c / 10;
    float mean = stat[(im * 32 + g) * 2 + 0];
    float rstd = stat[(im * 32 + g) * 2 + 1];
    tile[i][j] = (x[((size_t)(im * CH + c) << 10) + s0 + j] - mean) * rstd * gw[c] + gb[c];
  }
  __syncthreads();
  for (int t = threadIdx.x; t < 1024; t += 256) {
    int i = t >> 5, j = t & 31;
    xn[((size_t)(im * HW + s0 + i)) * CH + c0 + j] = f2b(tile[j][i]);
  }
}

// ---- temporal attention: one block per sequence, conflict-aware fp32 LDS ----
#define AROW 324   // row stride in floats: 324%32=4 (bank-spread), 16B-aligned
__global__ __launch_bounds__(256) void attention_kernel(const bf16* __restrict__ Q,
                                                        const bf16* __restrict__ K,
                                                        const bf16* __restrict__ V,
                                                        bf16* __restrict__ O) {
  __shared__ float q[16 * AROW];
  __shared__ float k[16 * AROW];
  __shared__ float v[16 * AROW];
  __shared__ float sc[HEADS * 16 * 16];
  const float SCALE = 0.15811388300841897f;
  int tid = threadIdx.x;
  int n = blockIdx.x;
  size_t base = (size_t)n * FRAMES * CH;
  for (int j = tid; j < 1280; j += 256) {
    int row = j / 80, off = (j - row * 80) * 4;
    int src = row * 320 + off;
    ushort4 uq = *(const ushort4*)(Q + base + src);
    ushort4 uk = *(const ushort4*)(K + base + src);
    ushort4 uv = *(const ushort4*)(V + base + src);
    float* qd = &q[row * AROW + off];
    float* kd = &k[row * AROW + off];
    float* vd = &v[row * AROW + off];
    qd[0] = bfbits2f(uq.x) * SCALE; qd[1] = bfbits2f(uq.y) * SCALE;
    qd[2] = bfbits2f(uq.z) * SCALE; qd[3] = bfbits2f(uq.w) * SCALE;
    kd[0] = bfbits2f(uk.x); kd[1] = bfbits2f(uk.y);
    kd[2] = bfbits2f(uk.z); kd[3] = bfbits2f(uk.w);
    vd[0] = bfbits2f(uv.x); vd[1] = bfbits2f(uv.y);
    vd[2] = bfbits2f(uv.z); vd[3] = bfbits2f(uv.w);
  }
  __syncthreads();
  {
    int h = tid >> 5, sub = tid & 31, qf = sub >> 1, kfg = sub & 1;
    const float* qrow = &q[qf * AROW + h * DHEAD];
    float s[8] = {0.f, 0.f, 0.f, 0.f, 0.f, 0.f, 0.f, 0.f};
#pragma unroll
    for (int d4 = 0; d4 < 10; ++d4) {
      float4 qv = *(const float4*)(qrow + d4 * 4);
#pragma unroll
      for (int i = 0; i < 8; ++i) {
        const float* krow = &k[(kfg * 8 + i) * AROW + h * DHEAD];
        float4 kv = *(const float4*)(krow + d4 * 4);
        s[i] += qv.x * kv.x + qv.y * kv.y + qv.z * kv.z + qv.w * kv.w;
      }
    }
    float* dst = &sc[(h * 16 + qf) * 16 + kfg * 8];
#pragma unroll
    for (int i = 0; i < 8; ++i) dst[i] = s[i];
  }
  __syncthreads();
  if (tid < 128) {
    float* r = &sc[tid * 16];
    float mx = r[0];
#pragma unroll
    for (int i = 1; i < 16; ++i) mx = fmaxf(mx, r[i]);
    float sum = 0.f;
#pragma unroll
    for (int i = 0; i < 16; ++i) { float e = expf(r[i] - mx); r[i] = e; sum += e; }
    float inv = 1.0f / sum;
#pragma unroll
    for (int i = 0; i < 16; ++i) r[i] *= inv;
  }
  __syncthreads();
  for (int g = tid; g < 1280; g += 256) {
    int qf = g / 80, c4 = g - qf * 80;
    int h = c4 / 10;
    const float* p = &sc[(h * 16 + qf) * 16];
    float4 o = {0.f, 0.f, 0.f, 0.f};
#pragma unroll
    for (int kf = 0; kf < 16; ++kf) {
      float pv = p[kf];
      float4 vv = *(const float4*)&v[kf * AROW + c4 * 4];
      o.x += pv * vv.x; o.y += pv * vv.y; o.z += pv * vv.z; o.w += pv * vv.w;
    }
    ushort4 u;
    u.x = f2bfbits(o.x); u.y = f2bfbits(o.y);
    u.z = f2bfbits(o.z); u.w = f2bfbits(o.w);
    *(ushort4*)(O + base + qf * 320 + c4 * 4) = u;
  }
}

// ---- final: tokens -> [img][c][s] + fp32 spatial residual; fp32 out ----
__global__ __launch_bounds__(256) void final_kernel(const bf16* __restrict__ proj,
                                                    const float* __restrict__ x,
                                                    float* __restrict__ out) {
  __shared__ float tile[32][33];
  int st = blockIdx.x, ct = blockIdx.y, im = blockIdx.z;
  int c0 = ct * 32, s0 = st * 32;
  for (int t = threadIdx.x; t < 1024; t += 256) {
    int i = t >> 5, j = t & 31;
    tile[i][j] = b2f(proj[((size_t)(im * HW + s0 + i)) * CH + c0 + j]);
  }
  __syncthreads();
  for (int t = threadIdx.x; t < 1024; t += 256) {
    int i = t >> 5, j = t & 31;
    size_t idx = ((size_t)(im * CH + c0 + i) << 10) + s0 + j;
    out[idx] = tile[j][i] + x[idx];
  }
}

extern "C" void kernel_launch(void* const* d_in, const int* in_sizes, int n_in,
                              void* d_out, int out_size, void* d_ws, size_t ws_size,
                              hipStream_t stream) {
  const float* x      = (const float*)d_in[0];
  const float* gn_w   = (const float*)d_in[1];
  const float* gn_b   = (const float*)d_in[2];
  const float* pin_w  = (const float*)d_in[3];
  const float* pin_b  = (const float*)d_in[4];
  const float* ffln_w = (const float*)d_in[19];
  const float* ffln_b = (const float*)d_in[20];
  const float* ff_w1  = (const float*)d_in[21];
  const float* ff_b1  = (const float*)d_in[22];
  const float* ff_w2  = (const float*)d_in[23];
  const float* ff_b2  = (const float*)d_in[24];
  const float* pout_w = (const float*)d_in[25];
  const float* pout_b = (const float*)d_in[26];

  const size_t NTC = (size_t)NT * CH;
  bf16* W0 = (bf16*)d_ws;              // hs residual stream (spatial token order)
  bf16* W1 = W0 + NTC;
  bf16* W2 = W1 + NTC;
  bf16* W3 = W2 + NTC;
  bf16* OB = (bf16*)d_out;             // scratch until final_kernel
  float* gnstat = (float*)d_out;
  bf16* WT = (bf16*)d_out + NTC;       // transposed weights region (upper half)
  bf16* wt_pin  = WT;
  bf16* wt_qkv1 = wt_pin + 102400;
  bf16* wt_wo1  = wt_qkv1 + 307200;
  bf16* wt_qkv2 = wt_wo1 + 102400;
  bf16* wt_wo2  = wt_qkv2 + 307200;
  bf16* wt_ff1  = wt_wo2 + 102400;
  bf16* wt_ff2  = wt_ff1 + 819200;
  bf16* wt_pout = wt_ff2 + 409600;
  float* petab  = (float*)(wt_pout + 102400);  // 16x320 fp32 PE table

  TDs td; int t0 = 0;
  auto add = [&](int i, const float* s, bf16* d, int K, int N) {
    td.d[i] = {s, d, K, N, t0}; t0 += (K / 32) * (N / 32);
  };
  add(0, pin_w, wt_pin, 320, 320);
  add(1, (const float*)d_in[7],  wt_qkv1,          320, 320);
  add(2, (const float*)d_in[8],  wt_qkv1 + 102400, 320, 320);
  add(3, (const float*)d_in[9],  wt_qkv1 + 204800, 320, 320);
  add(4, (const float*)d_in[10], wt_wo1,           320, 320);
  add(5, (const float*)d_in[14], wt_qkv2,          320, 320);
  add(6, (const float*)d_in[15], wt_qkv2 + 102400, 320, 320);
  add(7, (const float*)d_in[16], wt_qkv2 + 204800, 320, 320);
  add(8, (const float*)d_in[17], wt_wo2,           320, 320);
  add(9, ff_w1, wt_ff1, 320, 2560);
  add(10, ff_w2, wt_ff2, 1280, 320);
  add(11, pout_w, wt_pout, 320, 320);
  transpose_w_kernel<<<t0, 256, 0, stream>>>(td, 12);
  pe_table_kernel<<<20, 256, 0, stream>>>(petab);

  dim3 g_trans(32, 10, NIMG);
  dim3 g_gemm(NT / 128, 5);

  gn_stats_kernel<<<dim3(32, NIMG), 256, 0, stream>>>(x, gnstat);
  gn_apply_kernel<<<g_trans, 256, 0, stream>>>(x, gn_w, gn_b, gnstat, W1);
  gemm_mfma_kernel<<<g_gemm, 256, 0, stream>>>(W1, wt_pin, pin_b, nullptr,
                                               W0, W0, W0, NT, CH, 0);

  for (int blk = 0; blk < 2; ++blk) {
    const float* lnw = (const float*)d_in[5 + 7 * blk];
    const float* lnb = (const float*)d_in[6 + 7 * blk];
    const float* bo  = (const float*)d_in[11 + 7 * blk];
    bf16* wt_qkv = blk ? wt_qkv2 : wt_qkv1;
    bf16* wt_wo  = blk ? wt_wo2  : wt_wo1;

    // LN + rearrange-to-temporal + PE, wave-per-row
    ln_fused_kernel<<<NT / 4, 256, 0, stream>>>(W0, lnw, lnb, W2, petab, 1);
    // fused QKV: Q->W3, K->OB, V->W1 (temporal order)
    gemm_mfma_kernel<<<dim3(NT / 128, 15), 256, 0, stream>>>(W2, wt_qkv, nullptr, nullptr,
                                                             W3, OB, W1, NT, CH, 0);
    attention_kernel<<<NSEQ, 256, 0, stream>>>(W3, OB, W1, W2);
    // o-proj with fused rearrange-to-spatial + residual add into W0
    gemm_mfma_kernel<<<g_gemm, 256, 0, stream>>>(W2, wt_wo, bo, W0,
                                                 W0, W0, W0, NT, CH, 1);
  }

  ln_fused_kernel<<<NT / 4, 256, 0, stream>>>(W0, ffln_w, ffln_b, W1, nullptr, 0);
  const int MH = NT / 2;
  for (int h = 0; h < 2; ++h) {
    const bf16* Ah = W1 + (size_t)h * MH * CH;
    bf16* act = W2;
    gemm_mfma_geglu_kernel<<<dim3(MH / 128, 20), 256, 0, stream>>>(Ah, wt_ff1, ff_b1,
                                                                   act, MH, CH);
    bf16* hsh = W0 + (size_t)h * MH * CH;
    gemm_mfma_kernel<<<dim3(MH / 128, 5), 256, 0, stream>>>(act, wt_ff2, ff_b2, hsh,
                                                            hsh, hsh, hsh, MH, INNER, 0);
  }

  gemm_mfma_kernel<<<g_gemm, 256, 0, stream>>>(W0, wt_pout, pout_b, nullptr,
                                               W1, W1, W1, NT, CH, 0);
  final_kernel<<<g_trans, 256, 0, stream>>>(W1, x, (float*)d_out);
}